// Round 5
// baseline (185.983 us; speedup 1.0000x reference)
//
#include <hip/hip_runtime.h>
#include <hip/hip_bf16.h>

#define N_    8
#define H_    32
#define W_    32
#define C_    32
#define FH_   3
#define FW_   3
#define COUT_ 64
#define HO_   30
#define WO_   30
#define P_    (FH_ * FW_ * C_)   // 288
#define WPW   2                  // wo pixels per wave
#define NCOL  (WPW + FW_ - 1)    // 4 staged columns read per wave per iter
#define NCOLB 10                 // 8 pixels + 2 halo columns staged per block
#define NITER (FH_ * (C_ / 4))   // 24 flat (i,c4) iterations

// guaranteed 3-input max
__device__ __forceinline__ float max3f(float a, float b, float c) {
    float d;
    asm("v_max3_f32 %0, %1, %2, %3" : "=v"(d) : "v"(a), "v"(b), "v"(c));
    return d;
}

// Transpose k1,k2 from [P][COUT] to [COUT][P] so each lane (lane = co) can
// float4-load 4 consecutive p values.
__global__ void kt_kernel(const float* __restrict__ k1,
                          const float* __restrict__ k2,
                          float* __restrict__ k1t,
                          float* __restrict__ k2t) {
    int idx = blockIdx.x * 256 + threadIdx.x;
    if (idx < P_ * COUT_) {
        int p  = idx >> 6;        // / COUT_
        int co = idx & (COUT_ - 1);
        k1t[co * P_ + p] = k1[idx];
        k2t[co * P_ + p] = k2[idx];
    }
}

// load the 12 k-floats (3 j * 4 elems) per kernel for flat iter it_
#define LOADKV(b1, b2, it_) do {                                            \
    const int i_ = (it_) >> 3, c4_ = (it_) & 7;                             \
    if (TRANS) {                                                            \
        const int pb = i_ * (FW_ * C_) + c4_ * 4;                           \
        _Pragma("unroll")                                                   \
        for (int j = 0; j < FW_; ++j) {                                     \
            b1[j] = *reinterpret_cast<const float4*>(kb1 + pb + j * C_);    \
            b2[j] = *reinterpret_cast<const float4*>(kb2 + pb + j * C_);    \
        }                                                                   \
    } else {                                                                \
        _Pragma("unroll")                                                   \
        for (int j = 0; j < FW_; ++j) {                                     \
            const int pp = i_ * (FW_ * C_) + j * C_ + c4_ * 4;              \
            b1[j].x = kb1[(size_t)(pp + 0) * COUT_];                        \
            b1[j].y = kb1[(size_t)(pp + 1) * COUT_];                        \
            b1[j].z = kb1[(size_t)(pp + 2) * COUT_];                        \
            b1[j].w = kb1[(size_t)(pp + 3) * COUT_];                        \
            b2[j].x = kb2[(size_t)(pp + 0) * COUT_];                        \
            b2[j].y = kb2[(size_t)(pp + 1) * COUT_];                        \
            b2[j].z = kb2[(size_t)(pp + 2) * COUT_];                        \
            b2[j].w = kb2[(size_t)(pp + 3) * COUT_];                        \
        }                                                                   \
    }                                                                       \
} while (0)

// one flat iteration of the max-plus accumulation
#define COMPUTE(b1, b2, it_) do {                                           \
    const int i_ = (it_) >> 3, c4_ = (it_) & 7;                             \
    float4 a1r[NCOL], a2r[NCOL];                                            \
    _Pragma("unroll")                                                       \
    for (int q = 0; q < NCOL; ++q) {                                        \
        const int off = (i_ * NCOLB + w * WPW + q) * C_ + c4_ * 4;          \
        a1r[q] = *reinterpret_cast<const float4*>(lp1 + off);               \
        a2r[q] = *reinterpret_cast<const float4*>(lp2 + off);               \
    }                                                                       \
    _Pragma("unroll")                                                       \
    for (int j = 0; j < FW_; ++j) {                                         \
        _Pragma("unroll")                                                   \
        for (int p = 0; p < WPW; ++p) {                                     \
            const float4 a1 = a1r[p + j];                                   \
            const float4 a2 = a2r[p + j];                                   \
            m11[p] = max3f(m11[p], a1.x + b1[j].x, a1.y + b1[j].y);         \
            m11[p] = max3f(m11[p], a1.z + b1[j].z, a1.w + b1[j].w);         \
            m12[p] = max3f(m12[p], a1.x + b2[j].x, a1.y + b2[j].y);         \
            m12[p] = max3f(m12[p], a1.z + b2[j].z, a1.w + b2[j].w);         \
            m21[p] = max3f(m21[p], a2.x + b1[j].x, a2.y + b1[j].y);         \
            m21[p] = max3f(m21[p], a2.z + b1[j].z, a2.w + b1[j].w);         \
            m22[p] = max3f(m22[p], a2.x + b2[j].x, a2.y + b2[j].y);         \
            m22[p] = max3f(m22[p], a2.z + b2[j].z, a2.w + b2[j].w);         \
        }                                                                   \
    }                                                                       \
} while (0)

// Block = (n, ho, 8-pixel group): 4 waves, wave w computes wo = g*8 + w*2 + {0,1},
// all 64 output channels (lane = co). 8 accumulators/lane.
// 960 blocks * 4 waves = 3840 waves -> ~3.75 waves/SIMD for latency hiding.
template <bool TRANS>
__global__ __launch_bounds__(256, 4)
void bmorph_kernel(const float* __restrict__ x,
                   const float* __restrict__ k1,   // TRANS ? [COUT][P] : [P][COUT]
                   const float* __restrict__ k2,
                   const float* __restrict__ bias,
                   float* __restrict__ out) {
    __shared__ float lp1[FH_ * NCOLB * C_];   // 960 floats
    __shared__ float lp2[FH_ * NCOLB * C_];

    const int b   = blockIdx.x;
    const int g   = b & 3;
    const int ho  = (b >> 2) % HO_;
    const int n   = b / (4 * HO_);
    const int wob = g * 8;

    // ---- stage 3 rows x 10 cols x 32 c in log domain (240 float4 slots) ----
    {
        const int idx4 = threadIdx.x;
        if (idx4 < FH_ * NCOLB * (C_ / 4)) {          // 240
            const int c4 = idx4 & 7;
            const int cc = (idx4 >> 3) % NCOLB;
            const int r  = idx4 / (NCOLB * 8);
            int col = wob + cc; if (col > W_ - 1) col = W_ - 1;
            const float4 v = *reinterpret_cast<const float4*>(
                x + ((size_t)((n * H_ + ho + r) * W_ + col) * C_ + c4 * 4));
            float4 l1, l2;
            l1.x = __logf(fmaxf(v.x, 0.1f));  l2.x = __logf(fmaxf(-v.x, 0.1f));
            l1.y = __logf(fmaxf(v.y, 0.1f));  l2.y = __logf(fmaxf(-v.y, 0.1f));
            l1.z = __logf(fmaxf(v.z, 0.1f));  l2.z = __logf(fmaxf(-v.z, 0.1f));
            l1.w = __logf(fmaxf(v.w, 0.1f));  l2.w = __logf(fmaxf(-v.w, 0.1f));
            const int off = (r * NCOLB + cc) * C_ + c4 * 4;
            *reinterpret_cast<float4*>(lp1 + off) = l1;
            *reinterpret_cast<float4*>(lp2 + off) = l2;
        }
    }
    __syncthreads();

    const int w  = threadIdx.x >> 6;   // wave -> wo pair
    const int co = threadIdx.x & 63;   // lane -> output channel

    float m11[WPW], m12[WPW], m21[WPW], m22[WPW];
    #pragma unroll
    for (int p = 0; p < WPW; ++p) {
        m11[p] = -3.0e38f; m12[p] = -3.0e38f; m21[p] = -3.0e38f; m22[p] = -3.0e38f;
    }

    const float* kb1 = TRANS ? (k1 + (size_t)co * P_) : (k1 + co);
    const float* kb2 = TRANS ? (k2 + (size_t)co * P_) : (k2 + co);

    // ---- software-pipelined main loop: prefetch kv for it+1 while computing it
    float4 kvA1[FW_], kvA2[FW_], kvB1[FW_], kvB2[FW_];
    LOADKV(kvA1, kvA2, 0);
    #pragma unroll 1
    for (int it = 0; it < NITER; it += 2) {
        LOADKV(kvB1, kvB2, it + 1);
        COMPUTE(kvA1, kvA2, it);
        const int nx = (it + 2 < NITER) ? it + 2 : 0;   // clamped dummy at tail
        LOADKV(kvA1, kvA2, nx);
        COMPUTE(kvB1, kvB2, it + 1);
    }

    const float bz = bias[co];
    #pragma unroll
    for (int p = 0; p < WPW; ++p) {
        const int wo = wob + w * WPW + p;
        if (wo < WO_) {
            float r = __expf(m11[p]) - __expf(m12[p])
                    - __expf(m21[p]) + __expf(m22[p]) + bz;
            out[((size_t)(n * HO_ + ho) * WO_ + wo) * COUT_ + co] = r;
        }
    }
}

extern "C" void kernel_launch(void* const* d_in, const int* in_sizes, int n_in,
                              void* d_out, int out_size, void* d_ws, size_t ws_size,
                              hipStream_t stream) {
    const float* x    = (const float*)d_in[0];
    const float* k1   = (const float*)d_in[1];
    const float* k2   = (const float*)d_in[2];
    const float* bias = (const float*)d_in[3];
    float* out = (float*)d_out;

    const size_t kt_bytes = (size_t)P_ * COUT_ * sizeof(float);   // 73728 each
    const int nblocks = N_ * HO_ * 4;                             // 960

    if (ws_size >= 2 * kt_bytes) {
        float* k1t = (float*)d_ws;
        float* k2t = (float*)((char*)d_ws + kt_bytes);
        kt_kernel<<<(P_ * COUT_ + 255) / 256, 256, 0, stream>>>(k1, k2, k1t, k2t);
        bmorph_kernel<true><<<nblocks, 256, 0, stream>>>(x, k1t, k2t, bias, out);
    } else {
        bmorph_kernel<false><<<nblocks, 256, 0, stream>>>(x, k1, k2, bias, out);
    }
}

// Round 7
// 137.030 us; speedup vs baseline: 1.3572x; 1.3572x over previous
//
#include <hip/hip_runtime.h>
#include <hip/hip_bf16.h>
#include <math.h>

#define N_    8
#define H_    32
#define W_    32
#define C_    32
#define FH_   3
#define FW_   3
#define COUT_ 64
#define HO_   30
#define WO_   30
#define P_    (FH_ * FW_ * C_)   // 288
#define WPW   2                  // wo pixels per wave
#define NCOL  (WPW + FW_ - 1)    // 4 staged columns read per wave per iter
#define NCOLB 10                 // 8 pixels + 2 halo columns staged per block
#define NITER (FH_ * (C_ / 4))   // 24 flat (i,c4) iterations

typedef float v2f __attribute__((ext_vector_type(2)));

// guaranteed 3-input max
__device__ __forceinline__ float max3f(float a, float b, float c) {
    float d;
    asm("v_max3_f32 %0, %1, %2, %3" : "=v"(d) : "v"(a), "v"(b), "v"(c));
    return d;
}
// packed 2xf32 multiply (CDNA dual-issue packed fp32)
__device__ __forceinline__ v2f pkmul(v2f a, v2f b) {
    v2f d;
    asm("v_pk_mul_f32 %0, %1, %2" : "=v"(d) : "v"(a), "v"(b));
    return d;
}

// Precompute ek = exp(k) in pair-major layout: ekt[p>>1][co][p&1].
// Lane co then loads (ek[p][co], ek[p+1][co]) as one coalesced dwordx2.
__global__ void ek_kernel(const float* __restrict__ k1,
                          const float* __restrict__ k2,
                          float* __restrict__ e1,
                          float* __restrict__ e2) {
    int idx = blockIdx.x * 256 + threadIdx.x;
    if (idx < P_ * COUT_) {
        int p  = idx >> 6;        // / COUT_
        int co = idx & (COUT_ - 1);
        int dst = (p >> 1) * (COUT_ * 2) + co * 2 + (p & 1);
        e1[dst] = expf(k1[idx]);
        e2[dst] = expf(k2[idx]);
    }
}

// load 6 packed k-pairs (3 j * 2 pairs) per kernel for flat iter it_
// TRANS: ekt layout [144][64][2]; pair index = (i*3+j)*16 + c4*2 + q.
#define LOADKV(b1, b2, it_) do {                                            \
    const int i_ = (it_) >> 3, c4_ = (it_) & 7;                             \
    if (TRANS) {                                                            \
        const int base = (i_ * 48 + c4_ * 2) * (COUT_ * 2);                 \
        _Pragma("unroll")                                                   \
        for (int j = 0; j < FW_; ++j) {                                     \
            _Pragma("unroll")                                               \
            for (int q = 0; q < 2; ++q) {                                   \
                const int o = base + (j * 16 + q) * (COUT_ * 2);            \
                b1[j][q] = *reinterpret_cast<const v2f*>(kb1 + o);          \
                b2[j][q] = *reinterpret_cast<const v2f*>(kb2 + o);          \
            }                                                               \
        }                                                                   \
    } else {                                                                \
        _Pragma("unroll")                                                   \
        for (int j = 0; j < FW_; ++j) {                                     \
            _Pragma("unroll")                                               \
            for (int q = 0; q < 2; ++q) {                                   \
                const int pp = i_ * (FW_ * C_) + j * C_ + c4_ * 4 + q * 2;  \
                b1[j][q][0] = __expf(kb1[(size_t)(pp + 0) * COUT_]);        \
                b1[j][q][1] = __expf(kb1[(size_t)(pp + 1) * COUT_]);        \
                b2[j][q][0] = __expf(kb2[(size_t)(pp + 0) * COUT_]);        \
                b2[j][q][1] = __expf(kb2[(size_t)(pp + 1) * COUT_]);        \
            }                                                               \
        }                                                                   \
    }                                                                       \
} while (0)

// one flat iteration: packed products + max3 reduction
#define COMPUTE(b1, b2, it_) do {                                           \
    const int i_ = (it_) >> 3, c4_ = (it_) & 7;                             \
    v2f a1r[NCOL][2], a2r[NCOL][2];                                         \
    _Pragma("unroll")                                                       \
    for (int q = 0; q < NCOL; ++q) {                                        \
        const int off = (i_ * NCOLB + w * WPW + q) * C_ + c4_ * 4;          \
        a1r[q][0] = *reinterpret_cast<const v2f*>(ap + off);                \
        a1r[q][1] = *reinterpret_cast<const v2f*>(ap + off + 2);            \
        a2r[q][0] = *reinterpret_cast<const v2f*>(am + off);                \
        a2r[q][1] = *reinterpret_cast<const v2f*>(am + off + 2);            \
    }                                                                       \
    _Pragma("unroll")                                                       \
    for (int j = 0; j < FW_; ++j) {                                         \
        _Pragma("unroll")                                                   \
        for (int p = 0; p < WPW; ++p) {                                     \
            _Pragma("unroll")                                               \
            for (int q = 0; q < 2; ++q) {                                   \
                v2f t;                                                      \
                t = pkmul(a1r[p + j][q], b1[j][q]);                         \
                m11[p] = max3f(m11[p], t[0], t[1]);                         \
                t = pkmul(a1r[p + j][q], b2[j][q]);                         \
                m12[p] = max3f(m12[p], t[0], t[1]);                         \
                t = pkmul(a2r[p + j][q], b1[j][q]);                         \
                m21[p] = max3f(m21[p], t[0], t[1]);                         \
                t = pkmul(a2r[p + j][q], b2[j][q]);                         \
                m22[p] = max3f(m22[p], t[0], t[1]);                         \
            }                                                               \
        }                                                                   \
    }                                                                       \
} while (0)

// Block = (n, ho, 8-pixel group): 4 waves, wave w computes wo = g*8 + w*2 + {0,1},
// all 64 output channels (lane = co). Linear domain: no log/exp in hot path.
template <bool TRANS>
__global__ __launch_bounds__(256, 4)
void bmorph_kernel(const float* __restrict__ x,
                   const float* __restrict__ ek1,  // TRANS ? ekt pairs : raw k [P][COUT]
                   const float* __restrict__ ek2,
                   const float* __restrict__ bias,
                   float* __restrict__ out) {
    __shared__ float ap[FH_ * NCOLB * C_];   // max(x, 0.1)
    __shared__ float am[FH_ * NCOLB * C_];   // max(-x, 0.1)

    const int b   = blockIdx.x;
    const int g   = b & 3;
    const int ho  = (b >> 2) % HO_;
    const int n   = b / (4 * HO_);
    const int wob = g * 8;

    // ---- stage 3 rows x 10 cols x 32 c, both polarities (240 float4 slots) ----
    {
        const int idx4 = threadIdx.x;
        if (idx4 < FH_ * NCOLB * (C_ / 4)) {          // 240
            const int c4 = idx4 & 7;
            const int cc = (idx4 >> 3) % NCOLB;
            const int r  = idx4 / (NCOLB * 8);
            int col = wob + cc; if (col > W_ - 1) col = W_ - 1;
            const float4 v = *reinterpret_cast<const float4*>(
                x + ((size_t)((n * H_ + ho + r) * W_ + col) * C_ + c4 * 4));
            float4 lp, lm;
            lp.x = fmaxf(v.x, 0.1f);  lm.x = fmaxf(-v.x, 0.1f);
            lp.y = fmaxf(v.y, 0.1f);  lm.y = fmaxf(-v.y, 0.1f);
            lp.z = fmaxf(v.z, 0.1f);  lm.z = fmaxf(-v.z, 0.1f);
            lp.w = fmaxf(v.w, 0.1f);  lm.w = fmaxf(-v.w, 0.1f);
            const int off = (r * NCOLB + cc) * C_ + c4 * 4;
            *reinterpret_cast<float4*>(ap + off) = lp;
            *reinterpret_cast<float4*>(am + off) = lm;
        }
    }
    __syncthreads();

    const int w  = threadIdx.x >> 6;   // wave -> wo pair
    const int co = threadIdx.x & 63;   // lane -> output channel

    // all products are > 0, so 0 is a safe identity for max
    float m11[WPW] = {0.f, 0.f}, m12[WPW] = {0.f, 0.f};
    float m21[WPW] = {0.f, 0.f}, m22[WPW] = {0.f, 0.f};

    const float* kb1 = TRANS ? (ek1 + co * 2) : (ek1 + co);
    const float* kb2 = TRANS ? (ek2 + co * 2) : (ek2 + co);

    // ---- software-pipelined main loop: prefetch kv for it+1 while computing it
    v2f kA1[FW_][2], kA2[FW_][2], kB1[FW_][2], kB2[FW_][2];
    LOADKV(kA1, kA2, 0);
    #pragma unroll 1
    for (int it = 0; it < NITER; it += 2) {
        LOADKV(kB1, kB2, it + 1);
        COMPUTE(kA1, kA2, it);
        const int nx = (it + 2 < NITER) ? it + 2 : 0;   // clamped dummy at tail
        LOADKV(kA1, kA2, nx);
        COMPUTE(kB1, kB2, it + 1);
    }

    const float bz = bias[co];
    #pragma unroll
    for (int p = 0; p < WPW; ++p) {
        const int wo = wob + w * WPW + p;
        if (wo < WO_) {
            float r = m11[p] - m12[p] - m21[p] + m22[p] + bz;
            out[((size_t)(n * HO_ + ho) * WO_ + wo) * COUT_ + co] = r;
        }
    }
}

extern "C" void kernel_launch(void* const* d_in, const int* in_sizes, int n_in,
                              void* d_out, int out_size, void* d_ws, size_t ws_size,
                              hipStream_t stream) {
    const float* x    = (const float*)d_in[0];
    const float* k1   = (const float*)d_in[1];
    const float* k2   = (const float*)d_in[2];
    const float* bias = (const float*)d_in[3];
    float* out = (float*)d_out;

    const size_t ek_bytes = (size_t)P_ * COUT_ * sizeof(float);   // 73728 each
    const int nblocks = N_ * HO_ * 4;                             // 960

    if (ws_size >= 2 * ek_bytes) {
        float* e1 = (float*)d_ws;
        float* e2 = (float*)((char*)d_ws + ek_bytes);
        ek_kernel<<<(P_ * COUT_ + 255) / 256, 256, 0, stream>>>(k1, k2, e1, e2);
        bmorph_kernel<true><<<nblocks, 256, 0, stream>>>(x, e1, e2, bias, out);
    } else {
        bmorph_kernel<false><<<nblocks, 256, 0, stream>>>(x, k1, k2, bias, out);
    }
}

// Round 8
// 88.780 us; speedup vs baseline: 2.0949x; 1.5435x over previous
//
#include <hip/hip_runtime.h>
#include <math.h>

#define N_    8
#define H_    32
#define W_    32
#define C_    32
#define FH_   3
#define FW_   3
#define COUT_ 64
#define HO_   30
#define WO_   30
#define P_    288              // 3*3*32
#define NIJ   9
#define XPAD  36               // col stride (floats): 4-aligned, breaks pow2 banks
#define XROW  (W_ * XPAD)      // 1152

typedef float v2f __attribute__((ext_vector_type(2)));

// guaranteed 3-input max
__device__ __forceinline__ float max3f(float a, float b, float c) {
    float d;
    asm("v_max3_f32 %0, %1, %2, %3" : "=v"(d) : "v"(a), "v"(b), "v"(c));
    return d;
}
// packed 2xf32 multiply
__device__ __forceinline__ v2f pkmul(v2f a, v2f b) {
    v2f d;
    asm("v_pk_mul_f32 %0, %1, %2" : "=v"(d) : "v"(a), "v"(b));
    return d;
}

// Precompute e^k, co-major pair layout: e[co][pair*2 + (p&1)], pair = p>>1.
// Row co holds 288 consecutive floats; block (i,j) = 32 consecutive floats.
__global__ void ek_kernel(const float* __restrict__ k1,
                          const float* __restrict__ k2,
                          float* __restrict__ e1,
                          float* __restrict__ e2) {
    int idx = blockIdx.x * 256 + threadIdx.x;
    if (idx < P_ * COUT_) {
        int p  = idx >> 6;         // / 64
        int co = idx & 63;
        int dst = co * P_ + (p >> 1) * 2 + (p & 1);
        e1[dst] = expf(k1[idx]);
        e2[dst] = expf(k2[idx]);
    }
}

// Fallback (ws too small): naive but correct.
__global__ void naive_kernel(const float* __restrict__ x,
                             const float* __restrict__ k1,
                             const float* __restrict__ k2,
                             const float* __restrict__ bias,
                             float* __restrict__ out) {
    int idx = blockIdx.x * 256 + threadIdx.x;
    if (idx >= N_ * HO_ * WO_ * COUT_) return;
    int co = idx & 63, pix = idx >> 6;
    int wo = pix % WO_, t = pix / WO_, ho = t % HO_, n = t / HO_;
    float m11 = 0, m12 = 0, m21 = 0, m22 = 0;
    for (int i = 0; i < 3; ++i)
        for (int j = 0; j < 3; ++j)
            for (int c = 0; c < 32; ++c) {
                float v  = x[((size_t)(n * H_ + ho + i) * W_ + wo + j) * C_ + c];
                float a1 = fmaxf(v, 0.1f), a2 = fmaxf(-v, 0.1f);
                int p = (i * 3 + j) * 32 + c;
                float q1 = __expf(k1[(size_t)p * 64 + co]);
                float q2 = __expf(k2[(size_t)p * 64 + co]);
                m11 = fmaxf(m11, a1 * q1); m12 = fmaxf(m12, a1 * q2);
                m21 = fmaxf(m21, a2 * q1); m22 = fmaxf(m22, a2 * q2);
            }
    out[idx] = m11 - m12 - m21 + m22 + bias[co];
}

// Block = (n, ho, co-half): 4 waves, wave w owns co chunk [cohalf*32+w*8, +8).
// Lane = (c-half, col): lane reduces 16 of 32 channels of pixel (ho, col);
// halves merged by shfl_xor(32) at the end. k staged per-wave into LDS
// (double-buffered per (i,j) block), read as wave-uniform broadcasts.
// No global loads and no barriers in the main loop.
__global__ __launch_bounds__(256, 2)
void bmorph_kernel(const float* __restrict__ x,
                   const float* __restrict__ e1,   // [64][288] co-major pairs
                   const float* __restrict__ e2,
                   const float* __restrict__ bias,
                   float* __restrict__ out) {
    __shared__ float xs[FH_ * XROW];        // 3456 floats = 13.8 KB
    __shared__ float k1b[4][2][256];        // per-wave double-buffered k blocks
    __shared__ float k2b[4][2][256];        // 16 KB total

    const int b      = blockIdx.x;
    const int cohalf = b & 1;
    const int ho     = (b >> 1) % HO_;
    const int n      = b / (2 * HO_);

    // ---- stage x rows ho..ho+2 (3072 contiguous floats) ----
    const float* xsrc = x + (size_t)(n * H_ + ho) * (W_ * C_);
    #pragma unroll
    for (int r = 0; r < 3; ++r) {
        int idx4 = threadIdx.x + r * 256;            // 0..767 float4 slots
        float4 v = *reinterpret_cast<const float4*>(xsrc + (size_t)idx4 * 4);
        int row = idx4 >> 8;
        int rem = idx4 & 255;
        int col = rem >> 3;
        int c4  = rem & 7;
        *reinterpret_cast<float4*>(xs + row * XROW + col * XPAD + c4 * 4) = v;
    }

    const int w     = threadIdx.x >> 6;
    const int lane  = threadIdx.x & 63;
    const int hh    = lane >> 5;            // c-half
    const int col   = lane & 31;            // pixel column (30,31 idle for output)
    const int coch  = cohalf * 32 + w * 8;  // wave's first co

    // k-staging roles: lane -> (co row, 4-float chunk)
    const int kco = lane >> 3;              // 0..7
    const int kc8 = lane & 7;               // 0..7
    const float* g1 = e1 + (size_t)(coch + kco) * P_ + kc8 * 4;
    const float* g2 = e2 + (size_t)(coch + kco) * P_ + kc8 * 4;
    float* kw1 = &k1b[w][0][kco * 32 + kc8 * 4];
    float* kw2 = &k2b[w][0][kco * 32 + kc8 * 4];

    float m11[8], m12[8], m21[8], m22[8];
    #pragma unroll
    for (int q = 0; q < 8; ++q) { m11[q] = 0.f; m12[q] = 0.f; m21[q] = 0.f; m22[q] = 0.f; }

    // ---- prologue: k block for ij=0 into buf0; start load of ij=1 ----
    float4 gA1 = *reinterpret_cast<const float4*>(g1);
    float4 gA2 = *reinterpret_cast<const float4*>(g2);
    *reinterpret_cast<float4*>(kw1) = gA1;
    *reinterpret_cast<float4*>(kw2) = gA2;
    gA1 = *reinterpret_cast<const float4*>(g1 + 32);
    gA2 = *reinterpret_cast<const float4*>(g2 + 32);

    __syncthreads();   // xs ready (k bufs are wave-private)

    #pragma unroll 1
    for (int ij = 0; ij < NIJ; ++ij) {
        const int i_ = ij / 3;
        const int j_ = ij - i_ * 3;
        const float* kr1 = &k1b[w][ij & 1][0];
        const float* kr2 = &k2b[w][ij & 1][0];
        int ccol = col + j_; if (ccol > W_ - 1) ccol = W_ - 1;   // idle-lane clamp
        const float* ax = xs + i_ * XROW + ccol * XPAD + hh * 16;

        #pragma unroll
        for (int ch = 0; ch < 2; ++ch) {
            v2f a1[4], a2[4];
            #pragma unroll
            for (int q = 0; q < 4; ++q) {
                v2f xa = *reinterpret_cast<const v2f*>(ax + ch * 8 + q * 2);
                a1[q][0] = fmaxf(xa[0], 0.1f);   a1[q][1] = fmaxf(xa[1], 0.1f);
                a2[q][0] = fmaxf(-xa[0], 0.1f);  a2[q][1] = fmaxf(-xa[1], 0.1f);
            }
            #pragma unroll
            for (int co8 = 0; co8 < 8; ++co8) {
                const int kb = co8 * 32 + hh * 16 + ch * 8;
                float4 t1a = *reinterpret_cast<const float4*>(kr1 + kb);
                float4 t1b = *reinterpret_cast<const float4*>(kr1 + kb + 4);
                float4 t2a = *reinterpret_cast<const float4*>(kr2 + kb);
                float4 t2b = *reinterpret_cast<const float4*>(kr2 + kb + 4);
                v2f k1v[4], k2v[4];
                k1v[0] = (v2f){t1a.x, t1a.y}; k1v[1] = (v2f){t1a.z, t1a.w};
                k1v[2] = (v2f){t1b.x, t1b.y}; k1v[3] = (v2f){t1b.z, t1b.w};
                k2v[0] = (v2f){t2a.x, t2a.y}; k2v[1] = (v2f){t2a.z, t2a.w};
                k2v[2] = (v2f){t2b.x, t2b.y}; k2v[3] = (v2f){t2b.z, t2b.w};
                #pragma unroll
                for (int q = 0; q < 4; ++q) {
                    v2f t;
                    t = pkmul(a1[q], k1v[q]); m11[co8] = max3f(m11[co8], t[0], t[1]);
                    t = pkmul(a1[q], k2v[q]); m12[co8] = max3f(m12[co8], t[0], t[1]);
                    t = pkmul(a2[q], k1v[q]); m21[co8] = max3f(m21[co8], t[0], t[1]);
                    t = pkmul(a2[q], k2v[q]); m22[co8] = max3f(m22[co8], t[0], t[1]);
                }
            }
        }

        // per-wave k pipeline: write staged block ij+1, start load of ij+2
        if (ij < NIJ - 1) {
            float* w1 = kw1 + ((ij + 1) & 1) * 256;
            float* w2 = kw2 + ((ij + 1) & 1) * 256;
            *reinterpret_cast<float4*>(w1) = gA1;
            *reinterpret_cast<float4*>(w2) = gA2;
            if (ij < NIJ - 2) {
                gA1 = *reinterpret_cast<const float4*>(g1 + (ij + 2) * 32);
                gA2 = *reinterpret_cast<const float4*>(g2 + (ij + 2) * 32);
            }
        }
    }

    // ---- merge c-halves, combine, store ----
    float r8[8];
    #pragma unroll
    for (int co8 = 0; co8 < 8; ++co8) {
        float a = fmaxf(m11[co8], __shfl_xor(m11[co8], 32));
        float bq = fmaxf(m12[co8], __shfl_xor(m12[co8], 32));
        float c = fmaxf(m21[co8], __shfl_xor(m21[co8], 32));
        float d = fmaxf(m22[co8], __shfl_xor(m22[co8], 32));
        r8[co8] = a - bq - c + d + bias[coch + co8];
    }
    if (hh == 0 && col < WO_) {
        float* op = out + ((size_t)(n * HO_ + ho) * WO_ + col) * COUT_ + coch;
        *reinterpret_cast<float4*>(op)     = make_float4(r8[0], r8[1], r8[2], r8[3]);
        *reinterpret_cast<float4*>(op + 4) = make_float4(r8[4], r8[5], r8[6], r8[7]);
    }
}

extern "C" void kernel_launch(void* const* d_in, const int* in_sizes, int n_in,
                              void* d_out, int out_size, void* d_ws, size_t ws_size,
                              hipStream_t stream) {
    const float* x    = (const float*)d_in[0];
    const float* k1   = (const float*)d_in[1];
    const float* k2   = (const float*)d_in[2];
    const float* bias = (const float*)d_in[3];
    float* out = (float*)d_out;

    const size_t ek_bytes = (size_t)P_ * COUT_ * sizeof(float);   // 73728 each

    if (ws_size >= 2 * ek_bytes) {
        float* e1 = (float*)d_ws;
        float* e2 = (float*)((char*)d_ws + ek_bytes);
        ek_kernel<<<(P_ * COUT_ + 255) / 256, 256, 0, stream>>>(k1, k2, e1, e2);
        bmorph_kernel<<<N_ * HO_ * 2, 256, 0, stream>>>(x, e1, e2, bias, out);
    } else {
        int tot = N_ * HO_ * WO_ * COUT_;
        naive_kernel<<<(tot + 255) / 256, 256, 0, stream>>>(x, k1, k2, bias, out);
    }
}

// Round 10
// 83.553 us; speedup vs baseline: 2.2259x; 1.0626x over previous
//
#include <hip/hip_runtime.h>
#include <hip/hip_fp16.h>
#include <math.h>

#define N_    8
#define H_    32
#define W_    32
#define C_    32
#define COUT_ 64
#define HO_   30
#define WO_   30
#define P_    288
#define ASTR  20   // dword stride per (row,col) cell: 16 half2 pairs + 4 pad (bank-uniform)
#define EK_DWORDS 18432   // 9 ij * 16 cog * 2 kern * 4 co4 * 16 cpair

// packed fp16 ops (2 elems/instr)
__device__ __forceinline__ unsigned pkmul16(unsigned a, unsigned b) {
    unsigned d; asm("v_pk_mul_f16 %0,%1,%2" : "=v"(d) : "v"(a), "v"(b)); return d;
}
__device__ __forceinline__ unsigned pkmax16(unsigned a, unsigned b) {
    unsigned d; asm("v_pk_max_f16 %0,%1,%2" : "=v"(d) : "v"(a), "v"(b)); return d;
}
__device__ __forceinline__ unsigned h2pack(float a, float b) {
    __half2 h = __halves2half2(__float2half(a), __float2half(b));
    return *reinterpret_cast<unsigned*>(&h);
}
__device__ __forceinline__ float h2red(unsigned u) {   // max(lo, hi)
    __half2 h = *reinterpret_cast<__half2*>(&u);
    return fmaxf(__low2float(h), __high2float(h));
}

// Precompute exp(k) as fp16 pairs, layout [ij(9)][cog(16)][kern(2)][co4(4)][cpair(16)]
// (18432 dwords total — holds BOTH kernels). One wave (co-group cog) pulls its
// per-ij block as 128 contiguous dwords.
__global__ void ek_kernel(const float* __restrict__ k1,
                          const float* __restrict__ k2,
                          unsigned* __restrict__ ekb) {
    int tid = blockIdx.x * 256 + threadIdx.x;
    if (tid >= EK_DWORDS) return;
    int cp   = tid & 15;
    int co4  = (tid >> 4) & 3;
    int kern = (tid >> 6) & 1;
    int cog  = (tid >> 7) & 15;
    int ij   = tid >> 11;
    int co   = cog * 4 + co4;
    int p0   = ij * 32 + cp * 2;
    const float* s = kern ? k2 : k1;
    float f0 = expf(s[(size_t)p0 * COUT_ + co]);
    float f1 = expf(s[(size_t)(p0 + 1) * COUT_ + co]);
    ekb[tid] = h2pack(f0, f1);
}

// Fallback (ws too small): naive but correct.
__global__ void naive_kernel(const float* __restrict__ x,
                             const float* __restrict__ k1,
                             const float* __restrict__ k2,
                             const float* __restrict__ bias,
                             float* __restrict__ out) {
    int idx = blockIdx.x * 256 + threadIdx.x;
    if (idx >= N_ * HO_ * WO_ * COUT_) return;
    int co = idx & 63, pix = idx >> 6;
    int wo = pix % WO_, t = pix / WO_, ho = t % HO_, n = t / HO_;
    float m11 = 0, m12 = 0, m21 = 0, m22 = 0;
    for (int i = 0; i < 3; ++i)
        for (int j = 0; j < 3; ++j)
            for (int c = 0; c < 32; ++c) {
                float v  = x[((size_t)(n * H_ + ho + i) * W_ + wo + j) * C_ + c];
                float a1 = fmaxf(v, 0.1f), a2 = fmaxf(-v, 0.1f);
                int p = (i * 3 + j) * 32 + c;
                float q1 = __expf(k1[(size_t)p * 64 + co]);
                float q2 = __expf(k2[(size_t)p * 64 + co]);
                m11 = fmaxf(m11, a1 * q1); m12 = fmaxf(m12, a1 * q2);
                m21 = fmaxf(m21, a2 * q1); m22 = fmaxf(m22, a2 * q2);
            }
    out[idx] = m11 - m12 - m21 + m22 + bias[co];
}

#define ACC8(AC, Aa, Ab, Ka, Kb)                                   \
    AC = pkmax16(AC, pkmul16(Aa.x, Ka.x));                         \
    AC = pkmax16(AC, pkmul16(Aa.y, Ka.y));                         \
    AC = pkmax16(AC, pkmul16(Aa.z, Ka.z));                         \
    AC = pkmax16(AC, pkmul16(Aa.w, Ka.w));                         \
    AC = pkmax16(AC, pkmul16(Ab.x, Kb.x));                         \
    AC = pkmax16(AC, pkmul16(Ab.y, Kb.y));                         \
    AC = pkmax16(AC, pkmul16(Ab.z, Kb.z));                         \
    AC = pkmax16(AC, pkmul16(Ab.w, Kb.w));

// Block = (n, ho, coq): 4 waves; wave w owns co [coq*16+w*4, +4), lane = (hh,col):
// col = pixel column, hh = c-half (merged via shfl_xor(32) at the end).
// Hot loop: fp16 packed mul/max only; a from LDS (pre-fmaxed pairs), k via
// per-wave global->LDS double buffer (1 b64 load + 1 b64 write per lane per ij).
__global__ __launch_bounds__(256, 4)
void bmorph_kernel(const float* __restrict__ x,
                   const unsigned* __restrict__ ekb,
                   const float* __restrict__ bias,
                   float* __restrict__ out) {
    __shared__ unsigned a1h[3 * 32 * ASTR];   // 1920 dwords
    __shared__ unsigned a2h[3 * 32 * ASTR];
    __shared__ unsigned kq[4 * 2 * 128];      // per-wave double-buffered k

    const int b   = blockIdx.x;
    const int coq = b & 3;
    const int ho  = (b >> 2) % HO_;
    const int n   = b / (4 * HO_);
    const int tid = threadIdx.x;

    // ---- stage a1/a2 as fp16 (c0,c1)-pairs: 768 float4 slots over 3 rows ----
    const float* xsrc = x + (size_t)(n * H_ + ho) * (W_ * C_);
    #pragma unroll
    for (int r = 0; r < 3; ++r) {
        int s = tid + r * 256;
        float4 v = *reinterpret_cast<const float4*>(xsrc + (size_t)s * 4);
        int row = s >> 8, rem = s & 255, cc = rem >> 3, q = rem & 7;
        uint2 p1 = make_uint2(h2pack(fmaxf(v.x, 0.1f), fmaxf(v.y, 0.1f)),
                              h2pack(fmaxf(v.z, 0.1f), fmaxf(v.w, 0.1f)));
        uint2 p2 = make_uint2(h2pack(fmaxf(-v.x, 0.1f), fmaxf(-v.y, 0.1f)),
                              h2pack(fmaxf(-v.z, 0.1f), fmaxf(-v.w, 0.1f)));
        int d = (row * 32 + cc) * ASTR + q * 2;
        *reinterpret_cast<uint2*>(a1h + d) = p1;
        *reinterpret_cast<uint2*>(a2h + d) = p2;
    }

    const int w      = tid >> 6;
    const int lane   = tid & 63;
    const int hh     = lane >> 5;
    const int col    = lane & 31;
    const int cog_w  = coq * 4 + w;      // 0..15
    const int cobase = cog_w * 4;

    unsigned acc[4][2][2];               // [co4][kern][sign]
    #pragma unroll
    for (int a = 0; a < 4; ++a)
        #pragma unroll
        for (int k = 0; k < 2; ++k) { acc[a][k][0] = 0u; acc[a][k][1] = 0u; }

    // per-wave k pipeline pointers
    const unsigned* gkb = ekb + cog_w * 128 + lane * 2;   // + ij*2048
    unsigned* kwp = kq + w * 256 + lane * 2;              // + buf*128

    uint2 gk = *reinterpret_cast<const uint2*>(gkb);
    *reinterpret_cast<uint2*>(kwp) = gk;                  // buf0 <- ij0
    gk = *reinterpret_cast<const uint2*>(gkb + 2048);     // prefetch ij1

    __syncthreads();   // a-tiles ready (kq is wave-private)

    #pragma unroll 1
    for (int ij = 0; ij < 9; ++ij) {
        const int buf = ij & 1;
        if (ij < 8) {
            *reinterpret_cast<uint2*>(kwp + (buf ^ 1) * 128) = gk;
            if (ij < 7) gk = *reinterpret_cast<const uint2*>(gkb + (ij + 2) * 2048);
        }
        const int i_ = ij / 3;
        const int j_ = ij - i_ * 3;
        int ccol = col + j_; if (ccol > W_ - 1) ccol = W_ - 1;  // dead-lane clamp

        const unsigned* a1p = a1h + (i_ * 32 + ccol) * ASTR + hh * 8;
        const unsigned* a2p = a2h + (i_ * 32 + ccol) * ASTR + hh * 8;
        uint4 A1a = *reinterpret_cast<const uint4*>(a1p);
        uint4 A1b = *reinterpret_cast<const uint4*>(a1p + 4);
        uint4 A2a = *reinterpret_cast<const uint4*>(a2p);
        uint4 A2b = *reinterpret_cast<const uint4*>(a2p + 4);

        const unsigned* kb = kq + w * 256 + buf * 128 + hh * 8;
        #pragma unroll
        for (int c4 = 0; c4 < 4; ++c4) {
            uint4 K1a = *reinterpret_cast<const uint4*>(kb + c4 * 16);
            uint4 K1b = *reinterpret_cast<const uint4*>(kb + c4 * 16 + 4);
            uint4 K2a = *reinterpret_cast<const uint4*>(kb + 64 + c4 * 16);
            uint4 K2b = *reinterpret_cast<const uint4*>(kb + 64 + c4 * 16 + 4);
            ACC8(acc[c4][0][0], A1a, A1b, K1a, K1b);
            ACC8(acc[c4][0][1], A2a, A2b, K1a, K1b);
            ACC8(acc[c4][1][0], A1a, A1b, K2a, K2b);
            ACC8(acc[c4][1][1], A2a, A2b, K2a, K2b);
        }
    }

    // ---- reduce pair-halves, merge c-halves across hh, combine, store ----
    const float4 bz = *reinterpret_cast<const float4*>(bias + cobase);
    const float* bzf = reinterpret_cast<const float*>(&bz);
    float r[4];
    #pragma unroll
    for (int c4 = 0; c4 < 4; ++c4) {
        float m11 = h2red(acc[c4][0][0]);
        float m12 = h2red(acc[c4][1][0]);
        float m21 = h2red(acc[c4][0][1]);
        float m22 = h2red(acc[c4][1][1]);
        m11 = fmaxf(m11, __shfl_xor(m11, 32));
        m12 = fmaxf(m12, __shfl_xor(m12, 32));
        m21 = fmaxf(m21, __shfl_xor(m21, 32));
        m22 = fmaxf(m22, __shfl_xor(m22, 32));
        r[c4] = m11 - m12 - m21 + m22 + bzf[c4];
    }
    if (hh == 0 && col < WO_) {
        float* op = out + ((size_t)(n * HO_ + ho) * WO_ + col) * COUT_ + cobase;
        *reinterpret_cast<float4*>(op) = make_float4(r[0], r[1], r[2], r[3]);
    }
}

extern "C" void kernel_launch(void* const* d_in, const int* in_sizes, int n_in,
                              void* d_out, int out_size, void* d_ws, size_t ws_size,
                              hipStream_t stream) {
    const float* x    = (const float*)d_in[0];
    const float* k1   = (const float*)d_in[1];
    const float* k2   = (const float*)d_in[2];
    const float* bias = (const float*)d_in[3];
    float* out = (float*)d_out;

    const size_t ek_bytes = (size_t)EK_DWORDS * sizeof(unsigned);   // 73728

    if (ws_size >= ek_bytes) {
        unsigned* ekb = (unsigned*)d_ws;
        ek_kernel<<<(EK_DWORDS + 255) / 256, 256, 0, stream>>>(k1, k2, ekb);
        bmorph_kernel<<<N_ * HO_ * 4, 256, 0, stream>>>(x, ekb, bias, out);
    } else {
        int tot = N_ * HO_ * WO_ * COUT_;
        naive_kernel<<<(tot + 255) / 256, 256, 0, stream>>>(x, k1, k2, bias, out);
    }
}